// Round 2
// baseline (1218.947 us; speedup 1.0000x reference)
//
#include <hip/hip_runtime.h>

#define T_ 128
#define N_ 1000
#define E_ 16000
#define F_ 397
#define H_ 128
#define KPAD1 416
#define NCH1 13
#define KPAD2 128
#define NCH2 4

typedef _Float16 f16;
typedef __attribute__((ext_vector_type(8))) _Float16 f16x8;
typedef __attribute__((ext_vector_type(4))) float f32x4;

// ---------------- W prep: split f32 -> f16 hi/lo, zero-pad K ----------------
__global__ void prep_w(const float* __restrict__ w, f16* __restrict__ hi,
                       f16* __restrict__ lo, int K, int KP, int rows) {
    int idx = blockIdx.x * 256 + threadIdx.x;
    if (idx >= rows * KP) return;
    int r = idx / KP, k = idx % KP;
    float v = (k < K) ? w[r * K + k] : 0.f;
    f16 h = (f16)v;
    hi[idx] = h;
    lo[idx] = (f16)(v - (float)h);
}

// ---------------- GEMM: C[M,128] = A[M,K] @ (Bhi+Blo)[128,K]^T (fp16 MFMA) --
template<int K, int KP, int NCH, bool A_F32>
__global__ __launch_bounds__(256)
void gemm_kernel(const void* __restrict__ Aptr, const f16* __restrict__ Bhi,
                 const f16* __restrict__ Blo, f16* __restrict__ C) {
    __shared__ f16 Alds[128 * 40];   // 32 k + 8 pad per row (80B, 16B-aligned)
    __shared__ f16 Bhlds[128 * 40];
    __shared__ f16 Bllds[128 * 40];
    int tid = threadIdx.x;
    int lane = tid & 63, wave = tid >> 6;
    int rowOff = (wave & 1) * 64, colOff = (wave >> 1) * 64;
    long blockRow = (long)blockIdx.x * 128;

    f32x4 acc[4][4] = {};

    for (int ch = 0; ch < NCH; ++ch) {
        __syncthreads();
        if constexpr (A_F32) {
            const float* A = (const float*)Aptr;
            int k = tid & 31, r0 = tid >> 5;
            int kg = ch * 32 + k;
            #pragma unroll
            for (int i = 0; i < 16; ++i) {
                int r = r0 + i * 8;
                float v = (kg < K) ? A[(blockRow + r) * (long)K + kg] : 0.f;
                Alds[r * 40 + k] = (f16)v;
            }
        } else {
            const f16* A = (const f16*)Aptr;
            int ik = tid & 15, r0 = tid >> 4;
            #pragma unroll
            for (int i = 0; i < 8; ++i) {
                int r = r0 + i * 16;
                const int* src = (const int*)(A + (blockRow + r) * (long)K + ch * 32);
                *(int*)&Alds[r * 40 + ik * 2] = src[ik];
            }
        }
        {
            int ik = tid & 15, r0 = tid >> 4;
            #pragma unroll
            for (int i = 0; i < 8; ++i) {
                int r = r0 + i * 16;
                const int* sh = (const int*)(Bhi + r * KP + ch * 32);
                const int* sl = (const int*)(Blo + r * KP + ch * 32);
                *(int*)&Bhlds[r * 40 + ik * 2] = sh[ik];
                *(int*)&Bllds[r * 40 + ik * 2] = sl[ik];
            }
        }
        __syncthreads();
        int lrow = lane & 15, koff = (lane >> 4) * 8;
        f16x8 a[4], bh[4], bl[4];
        #pragma unroll
        for (int i = 0; i < 4; ++i) {
            a[i]  = *(const f16x8*)&Alds[(rowOff + i * 16 + lrow) * 40 + koff];
            bh[i] = *(const f16x8*)&Bhlds[(colOff + i * 16 + lrow) * 40 + koff];
            bl[i] = *(const f16x8*)&Bllds[(colOff + i * 16 + lrow) * 40 + koff];
        }
        #pragma unroll
        for (int i = 0; i < 4; ++i)
            #pragma unroll
            for (int j = 0; j < 4; ++j) {
                acc[i][j] = __builtin_amdgcn_mfma_f32_16x16x32_f16(a[i], bh[j], acc[i][j], 0, 0, 0);
                acc[i][j] = __builtin_amdgcn_mfma_f32_16x16x32_f16(a[i], bl[j], acc[i][j], 0, 0, 0);
            }
    }
    int lcol = lane & 15, rbase = (lane >> 4) * 4;
    #pragma unroll
    for (int i = 0; i < 4; ++i)
        #pragma unroll
        for (int j = 0; j < 4; ++j)
            #pragma unroll
            for (int r = 0; r < 4; ++r) {
                long row = blockRow + rowOff + i * 16 + rbase + r;
                C[row * 128 + colOff + j * 16 + lcol] = (f16)acc[i][j][r];
            }
}

// ---------------- CSR build ----------------
__global__ void count_kernel(const int* __restrict__ ei, int* __restrict__ deg) {
    int t = blockIdx.y;
    int e = blockIdx.x * 256 + threadIdx.x;
    if (e < E_) {
        int dst = ei[(t * 2 + 1) * E_ + e];
        atomicAdd(&deg[t * N_ + dst], 1);
    }
}

__global__ void scan_kernel(const int* __restrict__ deg, int* __restrict__ offs,
                            int* __restrict__ cursor) {
    int t = blockIdx.x, tid = threadIdx.x;
    __shared__ int s[256];
    int d[4], sum = 0;
    #pragma unroll
    for (int q = 0; q < 4; ++q) {
        int idx = tid * 4 + q;
        d[q] = (idx < N_) ? deg[t * N_ + idx] : 0;
        sum += d[q];
    }
    s[tid] = sum;
    __syncthreads();
    for (int off = 1; off < 256; off <<= 1) {
        int v = (tid >= off) ? s[tid - off] : 0;
        __syncthreads();
        s[tid] += v;
        __syncthreads();
    }
    int excl = s[tid] - sum;
    #pragma unroll
    for (int q = 0; q < 4; ++q) {
        int idx = tid * 4 + q;
        if (idx < N_) { offs[t * (N_ + 1) + idx] = excl; cursor[t * N_ + idx] = excl; }
        excl += d[q];
    }
    if (tid == 255) offs[t * (N_ + 1) + N_] = excl;
}

__global__ void fill_kernel(const int* __restrict__ ei, int* __restrict__ cursor,
                            int* __restrict__ srcs) {
    int t = blockIdx.y;
    int e = blockIdx.x * 256 + threadIdx.x;
    if (e < E_) {
        int src = ei[t * 2 * E_ + e];
        int dst = ei[(t * 2 + 1) * E_ + e];
        int pos = atomicAdd(&cursor[t * N_ + dst], 1);
        srcs[t * E_ + pos] = src;
    }
}

// ------- agg: h = relu(Y[n] + sum_{src->n} Y[src] + b); optional mean-pool ----
template<bool POOL>
__global__ __launch_bounds__(256)
void agg_kernel(const f16* __restrict__ Yin, const int* __restrict__ offs,
                const int* __restrict__ srcs, const float* __restrict__ bias,
                f16* __restrict__ hout, float* __restrict__ pooled) {
    __shared__ f16 ylds[N_ * 32];  // 64,000 B
    int t = blockIdx.x >> 2, c = blockIdx.x & 3;
    int tid = threadIdx.x;
    const f16* Yt = Yin + (size_t)t * N_ * H_ + c * 32;
    for (int idx = tid; idx < N_ * 4; idx += 256) {
        int node = idx >> 2, q = idx & 3;
        *(f16x8*)&ylds[node * 32 + q * 8] = *(const f16x8*)(Yt + (size_t)node * H_ + q * 8);
    }
    __syncthreads();
    int d = tid & 31, g = tid >> 5;  // 8 node-groups of 32 lanes
    float b = bias[c * 32 + d];
    const int* offt = offs + t * (N_ + 1);
    const int* srct = srcs + t * E_;
    float poolacc = 0.f;
    for (int pass = 0; pass < 125; ++pass) {
        int n = pass * 8 + g;
        int rs = offt[n], re = offt[n + 1];
        float a = (float)ylds[n * 32 + d];
        float a0 = 0.f, a1 = 0.f, a2 = 0.f, a3 = 0.f;
        int e = rs;
        for (; e + 3 < re; e += 4) {
            int s0 = srct[e], s1 = srct[e + 1], s2 = srct[e + 2], s3 = srct[e + 3];
            a0 += (float)ylds[s0 * 32 + d];
            a1 += (float)ylds[s1 * 32 + d];
            a2 += (float)ylds[s2 * 32 + d];
            a3 += (float)ylds[s3 * 32 + d];
        }
        for (; e < re; ++e) a0 += (float)ylds[srct[e] * 32 + d];
        a += (a0 + a1) + (a2 + a3) + b;
        a = fmaxf(a, 0.f);
        if (POOL) poolacc += a;
        else hout[((size_t)t * N_ + n) * H_ + c * 32 + d] = (f16)a;
    }
    if (POOL) atomicAdd(&pooled[t * H_ + c * 32 + d], poolacc);
}

// ---------------- LSTM front-end ----------------
__global__ void seq_kernel(const float* __restrict__ pooled, const float* __restrict__ emb,
                           const int* __restrict__ dok, float* __restrict__ seq) {
    int idx = blockIdx.x * 256 + threadIdx.x;
    if (idx >= T_ * 136) return;
    int t = idx / 136, dd = idx % 136;
    seq[idx] = (dd < 128) ? pooled[t * H_ + dd] * (1.0f / N_)
                          : emb[dok[t] * 8 + (dd - 128)];
}

__global__ __launch_bounds__(256)
void gx_kernel(const float* __restrict__ seq, const float* __restrict__ w_ih,
               const float* __restrict__ b_ih, const float* __restrict__ b_hh,
               float* __restrict__ Gx) {
    __shared__ float x[136];
    int t = blockIdx.x >> 1;
    int j = (blockIdx.x & 1) * 256 + threadIdx.x;
    if (threadIdx.x < 136) x[threadIdx.x] = seq[t * 136 + threadIdx.x];
    __syncthreads();
    const float* w = w_ih + (size_t)j * 136;
    float acc = b_ih[j] + b_hh[j];
    #pragma unroll 8
    for (int k = 0; k < 136; ++k) acc += w[k] * x[k];
    Gx[t * 512 + j] = acc;
}

__global__ __launch_bounds__(1024)
void lstm_kernel(const float* __restrict__ Gx, const float* __restrict__ w_hh,
                 const float* __restrict__ w_fc, const float* __restrict__ b_fc,
                 float* __restrict__ out) {
    __shared__ __align__(16) float h_lds[128];
    __shared__ float g_lds[512];
    int tid = threadIdx.x;
    int j = tid >> 1, half = tid & 1;
    float whh[64];
    #pragma unroll
    for (int k = 0; k < 64; ++k) whh[k] = w_hh[j * 128 + half * 64 + k];
    float c = 0.f;
    if (tid < 128) h_lds[tid] = 0.f;
    __syncthreads();
    for (int t = 0; t < T_; ++t) {
        const f32x4* hv4 = (const f32x4*)(h_lds + half * 64);
        float acc = 0.f;
        #pragma unroll
        for (int k4 = 0; k4 < 16; ++k4) {
            f32x4 hv = hv4[k4];
            acc += whh[k4 * 4 + 0] * hv[0] + whh[k4 * 4 + 1] * hv[1]
                 + whh[k4 * 4 + 2] * hv[2] + whh[k4 * 4 + 3] * hv[3];
        }
        acc += __shfl_xor(acc, 1);
        if (half == 0) g_lds[j] = acc + Gx[t * 512 + j];
        __syncthreads();
        if (tid < 128) {
            float gi = g_lds[tid], gf = g_lds[128 + tid];
            float gg = g_lds[256 + tid], go = g_lds[384 + tid];
            float fi = 1.f / (1.f + __expf(-gi));
            float ff = 1.f / (1.f + __expf(-gf));
            float fo = 1.f / (1.f + __expf(-go));
            c = ff * c + fi * tanhf(gg);
            h_lds[tid] = fo * tanhf(c);
        }
        __syncthreads();
        if (tid < 64) {
            float v = h_lds[tid] * w_fc[tid] + h_lds[64 + tid] * w_fc[64 + tid];
            #pragma unroll
            for (int off = 32; off; off >>= 1) v += __shfl_down(v, off);
            if (tid == 0) out[t] = v + b_fc[0];
        }
    }
}

// ---------------- launch ----------------
extern "C" void kernel_launch(void* const* d_in, const int* in_sizes, int n_in,
                              void* d_out, int out_size, void* d_ws, size_t ws_size,
                              hipStream_t stream) {
    const float* x    = (const float*)d_in[0];
    const int*   ei   = (const int*)d_in[1];
    const int*   dok  = (const int*)d_in[2];
    const float* w1   = (const float*)d_in[3];
    const float* b1   = (const float*)d_in[4];
    const float* w2   = (const float*)d_in[5];
    const float* b2   = (const float*)d_in[6];
    const float* emb  = (const float*)d_in[7];
    const float* w_ih = (const float*)d_in[8];
    const float* w_hh = (const float*)d_in[9];
    const float* b_ih = (const float*)d_in[10];
    const float* b_hh = (const float*)d_in[11];
    const float* w_fc = (const float*)d_in[12];
    const float* b_fc = (const float*)d_in[13];
    float* out = (float*)d_out;

    char* ws = (char*)d_ws;
    size_t off = 0;
    auto alloc = [&](size_t bytes) {
        void* p = ws + off;
        off = (off + bytes + 255) & ~(size_t)255;
        return p;
    };
    f16*   Y      = (f16*)alloc((size_t)128000 * 128 * 2);  // Y, reused as Z
    f16*   h1     = (f16*)alloc((size_t)128000 * 128 * 2);
    f16*   b1hi   = (f16*)alloc((size_t)128 * KPAD1 * 2);
    f16*   b1lo   = (f16*)alloc((size_t)128 * KPAD1 * 2);
    f16*   b2hi   = (f16*)alloc((size_t)128 * KPAD2 * 2);
    f16*   b2lo   = (f16*)alloc((size_t)128 * KPAD2 * 2);
    int*   deg    = (int*)alloc((size_t)T_ * N_ * 4);
    int*   offs   = (int*)alloc((size_t)T_ * (N_ + 1) * 4);
    int*   cursor = (int*)alloc((size_t)T_ * N_ * 4);
    int*   srcs   = (int*)alloc((size_t)T_ * E_ * 4);
    float* pooled = (float*)alloc((size_t)T_ * H_ * 4);
    float* seq    = (float*)alloc((size_t)T_ * 136 * 4);
    float* Gx     = (float*)alloc((size_t)T_ * 512 * 4);

    hipMemsetAsync(deg, 0, (size_t)T_ * N_ * 4, stream);
    hipMemsetAsync(pooled, 0, (size_t)T_ * H_ * 4, stream);

    prep_w<<<(128 * KPAD1 + 255) / 256, 256, 0, stream>>>(w1, b1hi, b1lo, F_, KPAD1, 128);
    prep_w<<<(128 * KPAD2 + 255) / 256, 256, 0, stream>>>(w2, b2hi, b2lo, H_, KPAD2, 128);
    count_kernel<<<dim3(63, T_), 256, 0, stream>>>(ei, deg);
    scan_kernel<<<T_, 256, 0, stream>>>(deg, offs, cursor);
    fill_kernel<<<dim3(63, T_), 256, 0, stream>>>(ei, cursor, srcs);

    gemm_kernel<F_, KPAD1, NCH1, true><<<1000, 256, 0, stream>>>(x, b1hi, b1lo, Y);
    agg_kernel<false><<<512, 256, 0, stream>>>(Y, offs, srcs, b1, h1, nullptr);
    gemm_kernel<H_, KPAD2, NCH2, false><<<1000, 256, 0, stream>>>(h1, b2hi, b2lo, Y);
    agg_kernel<true><<<512, 256, 0, stream>>>(Y, offs, srcs, b2, nullptr, pooled);

    seq_kernel<<<(T_ * 136 + 255) / 256, 256, 0, stream>>>(pooled, emb, dok, seq);
    gx_kernel<<<256, 256, 0, stream>>>(seq, w_ih, b_ih, b_hh, Gx);
    lstm_kernel<<<1, 1024, 0, stream>>>(Gx, w_hh, w_fc, b_fc, out);
}

// Round 3
// 889.546 us; speedup vs baseline: 1.3703x; 1.3703x over previous
//
#include <hip/hip_runtime.h>

#define T_ 128
#define N_ 1000
#define E_ 16000
#define F_ 397
#define H_ 128
#define KPAD1 416
#define NCH1 13
#define KPAD2 128
#define NCH2 4

typedef _Float16 f16;
typedef __attribute__((ext_vector_type(4))) _Float16 f16x4;
typedef __attribute__((ext_vector_type(8))) _Float16 f16x8;
typedef __attribute__((ext_vector_type(4))) float f32x4;

// ---------------- W prep: split f32 -> f16 hi/lo, zero-pad K ----------------
__global__ void prep_w(const float* __restrict__ w, f16* __restrict__ hi,
                       f16* __restrict__ lo, int K, int KP, int rows) {
    int idx = blockIdx.x * 256 + threadIdx.x;
    if (idx >= rows * KP) return;
    int r = idx / KP, k = idx % KP;
    float v = (k < K) ? w[r * K + k] : 0.f;
    f16 h = (f16)v;
    hi[idx] = h;
    lo[idx] = (f16)(v - (float)h);
}

// ---------------- GEMM: C[M,128] = A[M,K] @ (Bhi+Blo)[128,K]^T (fp16 MFMA) --
template<int K, int KP, int NCH, bool A_F32>
__global__ __launch_bounds__(256)
void gemm_kernel(const void* __restrict__ Aptr, const f16* __restrict__ Bhi,
                 const f16* __restrict__ Blo, f16* __restrict__ C) {
    __shared__ f16 Alds[128 * 40];   // 32 k + 8 pad per row (80B, 16B-aligned)
    __shared__ f16 Bhlds[128 * 40];
    __shared__ f16 Bllds[128 * 40];
    int tid = threadIdx.x;
    int lane = tid & 63, wave = tid >> 6;
    int rowOff = (wave & 1) * 64, colOff = (wave >> 1) * 64;
    long blockRow = (long)blockIdx.x * 128;

    f32x4 acc[4][4] = {};

    for (int ch = 0; ch < NCH; ++ch) {
        __syncthreads();
        if constexpr (A_F32) {
            const float* A = (const float*)Aptr;
            int k = tid & 31, r0 = tid >> 5;
            int kg = ch * 32 + k;
            #pragma unroll
            for (int i = 0; i < 16; ++i) {
                int r = r0 + i * 8;
                float v = (kg < K) ? A[(blockRow + r) * (long)K + kg] : 0.f;
                Alds[r * 40 + k] = (f16)v;
            }
        } else {
            const f16* A = (const f16*)Aptr;
            int ik = tid & 15, r0 = tid >> 4;
            #pragma unroll
            for (int i = 0; i < 8; ++i) {
                int r = r0 + i * 16;
                const int* src = (const int*)(A + (blockRow + r) * (long)K + ch * 32);
                *(int*)&Alds[r * 40 + ik * 2] = src[ik];
            }
        }
        {
            int ik = tid & 15, r0 = tid >> 4;
            #pragma unroll
            for (int i = 0; i < 8; ++i) {
                int r = r0 + i * 16;
                const int* sh = (const int*)(Bhi + r * KP + ch * 32);
                const int* sl = (const int*)(Blo + r * KP + ch * 32);
                *(int*)&Bhlds[r * 40 + ik * 2] = sh[ik];
                *(int*)&Bllds[r * 40 + ik * 2] = sl[ik];
            }
        }
        __syncthreads();
        int lrow = lane & 15, koff = (lane >> 4) * 8;
        f16x8 a[4], bh[4], bl[4];
        #pragma unroll
        for (int i = 0; i < 4; ++i) {
            a[i]  = *(const f16x8*)&Alds[(rowOff + i * 16 + lrow) * 40 + koff];
            bh[i] = *(const f16x8*)&Bhlds[(colOff + i * 16 + lrow) * 40 + koff];
            bl[i] = *(const f16x8*)&Bllds[(colOff + i * 16 + lrow) * 40 + koff];
        }
        #pragma unroll
        for (int i = 0; i < 4; ++i)
            #pragma unroll
            for (int j = 0; j < 4; ++j) {
                acc[i][j] = __builtin_amdgcn_mfma_f32_16x16x32_f16(a[i], bh[j], acc[i][j], 0, 0, 0);
                acc[i][j] = __builtin_amdgcn_mfma_f32_16x16x32_f16(a[i], bl[j], acc[i][j], 0, 0, 0);
            }
    }
    int lcol = lane & 15, rbase = (lane >> 4) * 4;
    #pragma unroll
    for (int i = 0; i < 4; ++i)
        #pragma unroll
        for (int j = 0; j < 4; ++j)
            #pragma unroll
            for (int r = 0; r < 4; ++r) {
                long row = blockRow + rowOff + i * 16 + rbase + r;
                C[row * 128 + colOff + j * 16 + lcol] = (f16)acc[i][j][r];
            }
}

// ---------------- CSR build ----------------
__global__ void count_kernel(const int* __restrict__ ei, int* __restrict__ deg) {
    int t = blockIdx.y;
    int e = blockIdx.x * 256 + threadIdx.x;
    if (e < E_) {
        int dst = ei[(t * 2 + 1) * E_ + e];
        atomicAdd(&deg[t * N_ + dst], 1);
    }
}

__global__ void scan_kernel(const int* __restrict__ deg, int* __restrict__ offs,
                            int* __restrict__ cursor) {
    int t = blockIdx.x, tid = threadIdx.x;
    __shared__ int s[256];
    int d[4], sum = 0;
    #pragma unroll
    for (int q = 0; q < 4; ++q) {
        int idx = tid * 4 + q;
        d[q] = (idx < N_) ? deg[t * N_ + idx] : 0;
        sum += d[q];
    }
    s[tid] = sum;
    __syncthreads();
    for (int off = 1; off < 256; off <<= 1) {
        int v = (tid >= off) ? s[tid - off] : 0;
        __syncthreads();
        s[tid] += v;
        __syncthreads();
    }
    int excl = s[tid] - sum;
    #pragma unroll
    for (int q = 0; q < 4; ++q) {
        int idx = tid * 4 + q;
        if (idx < N_) { offs[t * (N_ + 1) + idx] = excl; cursor[t * N_ + idx] = excl; }
        excl += d[q];
    }
    if (tid == 255) offs[t * (N_ + 1) + N_] = excl;
}

__global__ void fill_kernel(const int* __restrict__ ei, int* __restrict__ cursor,
                            int* __restrict__ srcs) {
    int t = blockIdx.y;
    int e = blockIdx.x * 256 + threadIdx.x;
    if (e < E_) {
        int src = ei[t * 2 * E_ + e];
        int dst = ei[(t * 2 + 1) * E_ + e];
        int pos = atomicAdd(&cursor[t * N_ + dst], 1);
        srcs[t * E_ + pos] = src;
    }
}

// ------- agg: h = relu(Y[n] + sum_{src->n} Y[src] + b); optional mean-pool ----
// One 32-lane group per node, all 128 channels (f16x4 per lane), gather from L2
// (Y_t = 256 KB, L2-resident — no LDS staging). 8 groups/block, 8 nodes/group.
__device__ __forceinline__ f32x4 cvt4(f16x4 v) {
    f32x4 r;
    r[0] = (float)v[0]; r[1] = (float)v[1]; r[2] = (float)v[2]; r[3] = (float)v[3];
    return r;
}

template<bool POOL>
__global__ __launch_bounds__(256)
void agg_kernel(const f16* __restrict__ Yin, const int* __restrict__ offs,
                const int* __restrict__ srcs, const float* __restrict__ bias,
                f16* __restrict__ hout, float* __restrict__ pooled) {
    __shared__ f32x4 pl[8][32];
    int t = blockIdx.x, nb = blockIdx.y;
    int tid = threadIdx.x;
    int g = tid >> 5, l = tid & 31;           // group, lane-in-group
    const f16* __restrict__ Yt = Yin + (size_t)t * N_ * H_ + l * 4;
    const int* __restrict__ offt = offs + t * (N_ + 1);
    const int* __restrict__ srct = srcs + t * E_;
    f32x4 bv = *(const f32x4*)&bias[l * 4];
    f32x4 pacc = {0.f, 0.f, 0.f, 0.f};

    #pragma unroll
    for (int i = 0; i < 8; ++i) {
        int n = nb * 64 + g * 8 + i;
        if (n < N_) {
            int rs = offt[n], re = offt[n + 1];
            f32x4 acc  = cvt4(*(const f16x4*)&Yt[(size_t)n * H_]);  // self
            f32x4 acc2 = {0.f, 0.f, 0.f, 0.f};
            int e = rs;
            for (; e + 3 < re; e += 4) {
                int s0 = srct[e], s1 = srct[e + 1], s2 = srct[e + 2], s3 = srct[e + 3];
                f16x4 y0 = *(const f16x4*)&Yt[(size_t)s0 * H_];
                f16x4 y1 = *(const f16x4*)&Yt[(size_t)s1 * H_];
                f16x4 y2 = *(const f16x4*)&Yt[(size_t)s2 * H_];
                f16x4 y3 = *(const f16x4*)&Yt[(size_t)s3 * H_];
                acc  += cvt4(y0) + cvt4(y1);
                acc2 += cvt4(y2) + cvt4(y3);
            }
            for (; e < re; ++e)
                acc2 += cvt4(*(const f16x4*)&Yt[(size_t)srct[e] * H_]);
            f32x4 r = acc + acc2 + bv;
            r[0] = fmaxf(r[0], 0.f); r[1] = fmaxf(r[1], 0.f);
            r[2] = fmaxf(r[2], 0.f); r[3] = fmaxf(r[3], 0.f);
            if (POOL) {
                pacc += r;
            } else {
                f16x4 hv;
                hv[0] = (f16)r[0]; hv[1] = (f16)r[1]; hv[2] = (f16)r[2]; hv[3] = (f16)r[3];
                *(f16x4*)&hout[((size_t)t * N_ + n) * H_ + l * 4] = hv;
            }
        }
    }
    if (POOL) {
        pl[g][l] = pacc;
        __syncthreads();
        if (tid < 128) {
            const float* plf = (const float*)pl;
            float s = 0.f;
            #pragma unroll
            for (int gg = 0; gg < 8; ++gg) s += plf[gg * 128 + tid];
            atomicAdd(&pooled[t * H_ + tid], s);
        }
    }
}

// ---------------- LSTM front-end ----------------
__global__ void seq_kernel(const float* __restrict__ pooled, const float* __restrict__ emb,
                           const int* __restrict__ dok, float* __restrict__ seq) {
    int idx = blockIdx.x * 256 + threadIdx.x;
    if (idx >= T_ * 136) return;
    int t = idx / 136, dd = idx % 136;
    seq[idx] = (dd < 128) ? pooled[t * H_ + dd] * (1.0f / N_)
                          : emb[dok[t] * 8 + (dd - 128)];
}

__global__ __launch_bounds__(256)
void gx_kernel(const float* __restrict__ seq, const float* __restrict__ w_ih,
               const float* __restrict__ b_ih, const float* __restrict__ b_hh,
               float* __restrict__ Gx) {
    __shared__ float x[136];
    int t = blockIdx.x >> 1;
    int j = (blockIdx.x & 1) * 256 + threadIdx.x;
    if (threadIdx.x < 136) x[threadIdx.x] = seq[t * 136 + threadIdx.x];
    __syncthreads();
    const float* w = w_ih + (size_t)j * 136;
    float acc = b_ih[j] + b_hh[j];
    #pragma unroll 8
    for (int k = 0; k < 136; ++k) acc += w[k] * x[k];
    Gx[t * 512 + j] = acc;
}

__global__ __launch_bounds__(1024)
void lstm_kernel(const float* __restrict__ Gx, const float* __restrict__ w_hh,
                 const float* __restrict__ w_fc, const float* __restrict__ b_fc,
                 float* __restrict__ out) {
    __shared__ __align__(16) float h_lds[128];
    __shared__ float g_lds[512];
    int tid = threadIdx.x;
    int j = tid >> 1, half = tid & 1;
    float whh[64];
    #pragma unroll
    for (int k = 0; k < 64; ++k) whh[k] = w_hh[j * 128 + half * 64 + k];
    float c = 0.f;
    if (tid < 128) h_lds[tid] = 0.f;
    __syncthreads();
    for (int t = 0; t < T_; ++t) {
        const f32x4* hv4 = (const f32x4*)(h_lds + half * 64);
        float acc = 0.f;
        #pragma unroll
        for (int k4 = 0; k4 < 16; ++k4) {
            f32x4 hv = hv4[k4];
            acc += whh[k4 * 4 + 0] * hv[0] + whh[k4 * 4 + 1] * hv[1]
                 + whh[k4 * 4 + 2] * hv[2] + whh[k4 * 4 + 3] * hv[3];
        }
        acc += __shfl_xor(acc, 1);
        if (half == 0) g_lds[j] = acc + Gx[t * 512 + j];
        __syncthreads();
        if (tid < 128) {
            float gi = g_lds[tid], gf = g_lds[128 + tid];
            float gg = g_lds[256 + tid], go = g_lds[384 + tid];
            float fi = 1.f / (1.f + __expf(-gi));
            float ff = 1.f / (1.f + __expf(-gf));
            float fo = 1.f / (1.f + __expf(-go));
            c = ff * c + fi * tanhf(gg);
            h_lds[tid] = fo * tanhf(c);
        }
        __syncthreads();
        if (tid < 64) {
            float v = h_lds[tid] * w_fc[tid] + h_lds[64 + tid] * w_fc[64 + tid];
            #pragma unroll
            for (int off = 32; off; off >>= 1) v += __shfl_down(v, off);
            if (tid == 0) out[t] = v + b_fc[0];
        }
    }
}

// ---------------- launch ----------------
extern "C" void kernel_launch(void* const* d_in, const int* in_sizes, int n_in,
                              void* d_out, int out_size, void* d_ws, size_t ws_size,
                              hipStream_t stream) {
    const float* x    = (const float*)d_in[0];
    const int*   ei   = (const int*)d_in[1];
    const int*   dok  = (const int*)d_in[2];
    const float* w1   = (const float*)d_in[3];
    const float* b1   = (const float*)d_in[4];
    const float* w2   = (const float*)d_in[5];
    const float* b2   = (const float*)d_in[6];
    const float* emb  = (const float*)d_in[7];
    const float* w_ih = (const float*)d_in[8];
    const float* w_hh = (const float*)d_in[9];
    const float* b_ih = (const float*)d_in[10];
    const float* b_hh = (const float*)d_in[11];
    const float* w_fc = (const float*)d_in[12];
    const float* b_fc = (const float*)d_in[13];
    float* out = (float*)d_out;

    char* ws = (char*)d_ws;
    size_t off = 0;
    auto alloc = [&](size_t bytes) {
        void* p = ws + off;
        off = (off + bytes + 255) & ~(size_t)255;
        return p;
    };
    f16*   Y      = (f16*)alloc((size_t)128000 * 128 * 2);  // Y, reused as Z
    f16*   h1     = (f16*)alloc((size_t)128000 * 128 * 2);
    f16*   b1hi   = (f16*)alloc((size_t)128 * KPAD1 * 2);
    f16*   b1lo   = (f16*)alloc((size_t)128 * KPAD1 * 2);
    f16*   b2hi   = (f16*)alloc((size_t)128 * KPAD2 * 2);
    f16*   b2lo   = (f16*)alloc((size_t)128 * KPAD2 * 2);
    int*   deg    = (int*)alloc((size_t)T_ * N_ * 4);
    int*   offs   = (int*)alloc((size_t)T_ * (N_ + 1) * 4);
    int*   cursor = (int*)alloc((size_t)T_ * N_ * 4);
    int*   srcs   = (int*)alloc((size_t)T_ * E_ * 4);
    float* pooled = (float*)alloc((size_t)T_ * H_ * 4);
    float* seq    = (float*)alloc((size_t)T_ * 136 * 4);
    float* Gx     = (float*)alloc((size_t)T_ * 512 * 4);

    hipMemsetAsync(deg, 0, (size_t)T_ * N_ * 4, stream);
    hipMemsetAsync(pooled, 0, (size_t)T_ * H_ * 4, stream);

    prep_w<<<(128 * KPAD1 + 255) / 256, 256, 0, stream>>>(w1, b1hi, b1lo, F_, KPAD1, 128);
    prep_w<<<(128 * KPAD2 + 255) / 256, 256, 0, stream>>>(w2, b2hi, b2lo, H_, KPAD2, 128);
    count_kernel<<<dim3(63, T_), 256, 0, stream>>>(ei, deg);
    scan_kernel<<<T_, 256, 0, stream>>>(deg, offs, cursor);
    fill_kernel<<<dim3(63, T_), 256, 0, stream>>>(ei, cursor, srcs);

    gemm_kernel<F_, KPAD1, NCH1, true><<<1000, 256, 0, stream>>>(x, b1hi, b1lo, Y);
    agg_kernel<false><<<dim3(T_, 16), 256, 0, stream>>>(Y, offs, srcs, b1, h1, nullptr);
    gemm_kernel<H_, KPAD2, NCH2, false><<<1000, 256, 0, stream>>>(h1, b2hi, b2lo, Y);
    agg_kernel<true><<<dim3(T_, 16), 256, 0, stream>>>(Y, offs, srcs, b2, nullptr, pooled);

    seq_kernel<<<(T_ * 136 + 255) / 256, 256, 0, stream>>>(pooled, emb, dok, seq);
    gx_kernel<<<256, 256, 0, stream>>>(seq, w_ih, b_ih, b_hh, Gx);
    lstm_kernel<<<1, 1024, 0, stream>>>(Gx, w_hh, w_fc, b_fc, out);
}

// Round 4
// 783.220 us; speedup vs baseline: 1.5563x; 1.1358x over previous
//
#include <hip/hip_runtime.h>

#define T_ 128
#define N_ 1000
#define E_ 16000
#define F_ 397
#define H_ 128
#define KPAD1 416
#define NCH1 13
#define KPAD2 128
#define NCH2 4

typedef _Float16 f16;
typedef __attribute__((ext_vector_type(4))) _Float16 f16x4;
typedef __attribute__((ext_vector_type(8))) _Float16 f16x8;
typedef __attribute__((ext_vector_type(4))) float f32x4;

// ---------------- W prep: split f32 -> f16 hi/lo, zero-pad K ----------------
__global__ void prep_w(const float* __restrict__ w, f16* __restrict__ hi,
                       f16* __restrict__ lo, int K, int KP, int rows) {
    int idx = blockIdx.x * 256 + threadIdx.x;
    if (idx >= rows * KP) return;
    int r = idx / KP, k = idx % KP;
    float v = (k < K) ? w[r * K + k] : 0.f;
    f16 h = (f16)v;
    hi[idx] = h;
    lo[idx] = (f16)(v - (float)h);
}

// ---------------- GEMM: C[M,128] = A[M,K] @ (Bhi+Blo)[128,K]^T (fp16 MFMA) --
template<int K, int KP, int NCH, bool A_F32>
__global__ __launch_bounds__(256)
void gemm_kernel(const void* __restrict__ Aptr, const f16* __restrict__ Bhi,
                 const f16* __restrict__ Blo, f16* __restrict__ C) {
    __shared__ f16 Alds[128 * 40];   // 32 k + 8 pad per row (80B, 16B-aligned)
    __shared__ f16 Bhlds[128 * 40];
    __shared__ f16 Bllds[128 * 40];
    int tid = threadIdx.x;
    int lane = tid & 63, wave = tid >> 6;
    int rowOff = (wave & 1) * 64, colOff = (wave >> 1) * 64;
    long blockRow = (long)blockIdx.x * 128;

    f32x4 acc[4][4] = {};

    for (int ch = 0; ch < NCH; ++ch) {
        __syncthreads();
        if constexpr (A_F32) {
            const float* A = (const float*)Aptr;
            int k = tid & 31, r0 = tid >> 5;
            int kg = ch * 32 + k;
            #pragma unroll
            for (int i = 0; i < 16; ++i) {
                int r = r0 + i * 8;
                float v = (kg < K) ? A[(blockRow + r) * (long)K + kg] : 0.f;
                Alds[r * 40 + k] = (f16)v;
            }
        } else {
            const f16* A = (const f16*)Aptr;
            int ik = tid & 15, r0 = tid >> 4;
            #pragma unroll
            for (int i = 0; i < 8; ++i) {
                int r = r0 + i * 16;
                const int* src = (const int*)(A + (blockRow + r) * (long)K + ch * 32);
                *(int*)&Alds[r * 40 + ik * 2] = src[ik];
            }
        }
        {
            int ik = tid & 15, r0 = tid >> 4;
            #pragma unroll
            for (int i = 0; i < 8; ++i) {
                int r = r0 + i * 16;
                const int* sh = (const int*)(Bhi + r * KP + ch * 32);
                const int* sl = (const int*)(Blo + r * KP + ch * 32);
                *(int*)&Bhlds[r * 40 + ik * 2] = sh[ik];
                *(int*)&Bllds[r * 40 + ik * 2] = sl[ik];
            }
        }
        __syncthreads();
        int lrow = lane & 15, koff = (lane >> 4) * 8;
        f16x8 a[4], bh[4], bl[4];
        #pragma unroll
        for (int i = 0; i < 4; ++i) {
            a[i]  = *(const f16x8*)&Alds[(rowOff + i * 16 + lrow) * 40 + koff];
            bh[i] = *(const f16x8*)&Bhlds[(colOff + i * 16 + lrow) * 40 + koff];
            bl[i] = *(const f16x8*)&Bllds[(colOff + i * 16 + lrow) * 40 + koff];
        }
        #pragma unroll
        for (int i = 0; i < 4; ++i)
            #pragma unroll
            for (int j = 0; j < 4; ++j) {
                acc[i][j] = __builtin_amdgcn_mfma_f32_16x16x32_f16(a[i], bh[j], acc[i][j], 0, 0, 0);
                acc[i][j] = __builtin_amdgcn_mfma_f32_16x16x32_f16(a[i], bl[j], acc[i][j], 0, 0, 0);
            }
    }
    int lcol = lane & 15, rbase = (lane >> 4) * 4;
    #pragma unroll
    for (int i = 0; i < 4; ++i)
        #pragma unroll
        for (int j = 0; j < 4; ++j)
            #pragma unroll
            for (int r = 0; r < 4; ++r) {
                long row = blockRow + rowOff + i * 16 + rbase + r;
                C[row * 128 + colOff + j * 16 + lcol] = (f16)acc[i][j][r];
            }
}

// ---------------- CSR build ----------------
__global__ void count_kernel(const int* __restrict__ ei, int* __restrict__ deg) {
    int t = blockIdx.y;
    int e = blockIdx.x * 256 + threadIdx.x;
    if (e < E_) {
        int dst = ei[(t * 2 + 1) * E_ + e];
        atomicAdd(&deg[t * N_ + dst], 1);
    }
}

__global__ void scan_kernel(const int* __restrict__ deg, int* __restrict__ offs,
                            int* __restrict__ cursor) {
    int t = blockIdx.x, tid = threadIdx.x;
    __shared__ int s[256];
    int d[4], sum = 0;
    #pragma unroll
    for (int q = 0; q < 4; ++q) {
        int idx = tid * 4 + q;
        d[q] = (idx < N_) ? deg[t * N_ + idx] : 0;
        sum += d[q];
    }
    s[tid] = sum;
    __syncthreads();
    for (int off = 1; off < 256; off <<= 1) {
        int v = (tid >= off) ? s[tid - off] : 0;
        __syncthreads();
        s[tid] += v;
        __syncthreads();
    }
    int excl = s[tid] - sum;
    #pragma unroll
    for (int q = 0; q < 4; ++q) {
        int idx = tid * 4 + q;
        if (idx < N_) { offs[t * (N_ + 1) + idx] = excl; cursor[t * N_ + idx] = excl; }
        excl += d[q];
    }
    if (tid == 255) offs[t * (N_ + 1) + N_] = excl;
}

__global__ void fill_kernel(const int* __restrict__ ei, int* __restrict__ cursor,
                            int* __restrict__ srcs) {
    int t = blockIdx.y;
    int e = blockIdx.x * 256 + threadIdx.x;
    if (e < E_) {
        int src = ei[t * 2 * E_ + e];
        int dst = ei[(t * 2 + 1) * E_ + e];
        int pos = atomicAdd(&cursor[t * N_ + dst], 1);
        srcs[t * E_ + pos] = src;
    }
}

// ------- agg: h = relu(Y[n] + sum_{src->n} Y[src] + b); optional mean-pool ----
__device__ __forceinline__ f32x4 cvt4(f16x4 v) {
    f32x4 r;
    r[0] = (float)v[0]; r[1] = (float)v[1]; r[2] = (float)v[2]; r[3] = (float)v[3];
    return r;
}

template<bool POOL>
__global__ __launch_bounds__(256)
void agg_kernel(const f16* __restrict__ Yin, const int* __restrict__ offs,
                const int* __restrict__ srcs, const float* __restrict__ bias,
                f16* __restrict__ hout, float* __restrict__ pooled) {
    __shared__ f32x4 pl[8][32];
    int t = blockIdx.x, nb = blockIdx.y;
    int tid = threadIdx.x;
    int g = tid >> 5, l = tid & 31;           // group, lane-in-group
    const f16* __restrict__ Yt = Yin + (size_t)t * N_ * H_ + l * 4;
    const int* __restrict__ offt = offs + t * (N_ + 1);
    const int* __restrict__ srct = srcs + t * E_;
    f32x4 bv = *(const f32x4*)&bias[l * 4];
    f32x4 pacc = {0.f, 0.f, 0.f, 0.f};

    #pragma unroll
    for (int i = 0; i < 8; ++i) {
        int n = nb * 64 + g * 8 + i;
        if (n < N_) {
            int rs = offt[n], re = offt[n + 1];
            f32x4 acc  = cvt4(*(const f16x4*)&Yt[(size_t)n * H_]);  // self
            f32x4 acc2 = {0.f, 0.f, 0.f, 0.f};
            int e = rs;
            for (; e + 3 < re; e += 4) {
                int s0 = srct[e], s1 = srct[e + 1], s2 = srct[e + 2], s3 = srct[e + 3];
                f16x4 y0 = *(const f16x4*)&Yt[(size_t)s0 * H_];
                f16x4 y1 = *(const f16x4*)&Yt[(size_t)s1 * H_];
                f16x4 y2 = *(const f16x4*)&Yt[(size_t)s2 * H_];
                f16x4 y3 = *(const f16x4*)&Yt[(size_t)s3 * H_];
                acc  += cvt4(y0) + cvt4(y1);
                acc2 += cvt4(y2) + cvt4(y3);
            }
            for (; e < re; ++e)
                acc2 += cvt4(*(const f16x4*)&Yt[(size_t)srct[e] * H_]);
            f32x4 r = acc + acc2 + bv;
            r[0] = fmaxf(r[0], 0.f); r[1] = fmaxf(r[1], 0.f);
            r[2] = fmaxf(r[2], 0.f); r[3] = fmaxf(r[3], 0.f);
            if (POOL) {
                pacc += r;
            } else {
                f16x4 hv;
                hv[0] = (f16)r[0]; hv[1] = (f16)r[1]; hv[2] = (f16)r[2]; hv[3] = (f16)r[3];
                *(f16x4*)&hout[((size_t)t * N_ + n) * H_ + l * 4] = hv;
            }
        }
    }
    if (POOL) {
        pl[g][l] = pacc;
        __syncthreads();
        if (tid < 128) {
            const float* plf = (const float*)pl;
            float s = 0.f;
            #pragma unroll
            for (int gg = 0; gg < 8; ++gg) s += plf[gg * 128 + tid];
            atomicAdd(&pooled[t * H_ + tid], s);
        }
    }
}

// ---------------- LSTM front-end ----------------
__global__ void seq_kernel(const float* __restrict__ pooled, const float* __restrict__ emb,
                           const int* __restrict__ dok, float* __restrict__ seq) {
    int idx = blockIdx.x * 256 + threadIdx.x;
    if (idx >= T_ * 136) return;
    int t = idx / 136, dd = idx % 136;
    seq[idx] = (dd < 128) ? pooled[t * H_ + dd] * (1.0f / N_)
                          : emb[dok[t] * 8 + (dd - 128)];
}

__global__ __launch_bounds__(256)
void gx_kernel(const float* __restrict__ seq, const float* __restrict__ w_ih,
               const float* __restrict__ b_ih, const float* __restrict__ b_hh,
               float* __restrict__ Gx) {
    __shared__ float x[136];
    int t = blockIdx.x >> 1;
    int j = (blockIdx.x & 1) * 256 + threadIdx.x;
    if (threadIdx.x < 136) x[threadIdx.x] = seq[t * 136 + threadIdx.x];
    __syncthreads();
    const float* w = w_ih + (size_t)j * 136;
    float acc = b_ih[j] + b_hh[j];
    #pragma unroll 8
    for (int k = 0; k < 136; ++k) acc += w[k] * x[k];
    Gx[t * 512 + j] = acc;
}

// ---------------- LSTM recurrence: 512 threads = 4 k-slices x 128 channels ---
__device__ __forceinline__ float sigm_f(float x) {
    return __builtin_amdgcn_rcpf(1.f + __expf(-x));
}
__device__ __forceinline__ float tanh_f(float x) {
    float xx = fminf(fmaxf(x, -15.f), 15.f);
    float t = __expf(2.f * xx);
    return 1.f - 2.f * __builtin_amdgcn_rcpf(t + 1.f);
}

__global__ __launch_bounds__(512, 2)
void lstm_kernel(const float* __restrict__ Gx, const float* __restrict__ w_hh,
                 const float* __restrict__ w_fc, const float* __restrict__ b_fc,
                 float* __restrict__ out) {
    __shared__ __align__(16) float h_lds[128];
    __shared__ __align__(16) f32x4 pl[4][128];
    int tid = threadIdx.x;
    int s = tid >> 7, k = tid & 127;   // k-slice, channel
    // thread (s,k) holds W_hh rows {k,128+k,256+k,384+k}, cols [32s, 32s+32)
    f32x4 whh[4][8];
    #pragma unroll
    for (int g = 0; g < 4; ++g)
        #pragma unroll
        for (int q = 0; q < 8; ++q)
            whh[g][q] = *(const f32x4*)&w_hh[(g * 128 + k) * 128 + s * 32 + q * 4];
    float c = 0.f;
    float wfc0 = 0.f, wfc1 = 0.f;
    if (tid < 64) { wfc0 = w_fc[tid]; wfc1 = w_fc[64 + tid]; }
    float bfc = b_fc[0];
    float gx0 = 0.f, gx1 = 0.f, gx2 = 0.f, gx3 = 0.f;
    if (tid < 128) {
        gx0 = Gx[k]; gx1 = Gx[128 + k]; gx2 = Gx[256 + k]; gx3 = Gx[384 + k];
        h_lds[k] = 0.f;
    }
    __syncthreads();
    for (int t = 0; t < T_; ++t) {
        // partial dot over this thread's 32-wide k-slice, 4 gates
        const f32x4* h4 = (const f32x4*)h_lds + s * 8;
        f32x4 p0 = {0,0,0,0}, p1 = {0,0,0,0}, p2 = {0,0,0,0}, p3 = {0,0,0,0};
        #pragma unroll
        for (int q = 0; q < 8; ++q) {
            f32x4 v = h4[q];
            p0 += v * whh[0][q];
            p1 += v * whh[1][q];
            p2 += v * whh[2][q];
            p3 += v * whh[3][q];
        }
        f32x4 part;
        part[0] = (p0[0] + p0[1]) + (p0[2] + p0[3]);
        part[1] = (p1[0] + p1[1]) + (p1[2] + p1[3]);
        part[2] = (p2[0] + p2[1]) + (p2[2] + p2[3]);
        part[3] = (p3[0] + p3[1]) + (p3[2] + p3[3]);
        pl[s][k] = part;
        __syncthreads();
        if (tid < 128) {
            f32x4 gsum = pl[0][k] + pl[1][k] + pl[2][k] + pl[3][k];
            float gi = gsum[0] + gx0, gf = gsum[1] + gx1;
            float gg = gsum[2] + gx2, go = gsum[3] + gx3;
            // prefetch next step's Gx (hidden under next dot)
            int tn = (t + 1 < T_) ? t + 1 : t;
            const float* gp = Gx + tn * 512;
            gx0 = gp[k]; gx1 = gp[128 + k]; gx2 = gp[256 + k]; gx3 = gp[384 + k];
            float fi = sigm_f(gi), ff = sigm_f(gf), fo = sigm_f(go);
            c = ff * c + fi * tanh_f(gg);
            h_lds[k] = fo * tanh_f(c);
        }
        __syncthreads();
        if (tid < 64) {
            float v = h_lds[tid] * wfc0 + h_lds[64 + tid] * wfc1;
            #pragma unroll
            for (int off = 32; off; off >>= 1) v += __shfl_down(v, off);
            if (tid == 0) out[t] = v + bfc;
        }
    }
}

// ---------------- launch ----------------
extern "C" void kernel_launch(void* const* d_in, const int* in_sizes, int n_in,
                              void* d_out, int out_size, void* d_ws, size_t ws_size,
                              hipStream_t stream) {
    const float* x    = (const float*)d_in[0];
    const int*   ei   = (const int*)d_in[1];
    const int*   dok  = (const int*)d_in[2];
    const float* w1   = (const float*)d_in[3];
    const float* b1   = (const float*)d_in[4];
    const float* w2   = (const float*)d_in[5];
    const float* b2   = (const float*)d_in[6];
    const float* emb  = (const float*)d_in[7];
    const float* w_ih = (const float*)d_in[8];
    const float* w_hh = (const float*)d_in[9];
    const float* b_ih = (const float*)d_in[10];
    const float* b_hh = (const float*)d_in[11];
    const float* w_fc = (const float*)d_in[12];
    const float* b_fc = (const float*)d_in[13];
    float* out = (float*)d_out;

    char* ws = (char*)d_ws;
    size_t off = 0;
    auto alloc = [&](size_t bytes) {
        void* p = ws + off;
        off = (off + bytes + 255) & ~(size_t)255;
        return p;
    };
    f16*   Y      = (f16*)alloc((size_t)128000 * 128 * 2);  // Y, reused as Z
    f16*   h1     = (f16*)alloc((size_t)128000 * 128 * 2);
    f16*   b1hi   = (f16*)alloc((size_t)128 * KPAD1 * 2);
    f16*   b1lo   = (f16*)alloc((size_t)128 * KPAD1 * 2);
    f16*   b2hi   = (f16*)alloc((size_t)128 * KPAD2 * 2);
    f16*   b2lo   = (f16*)alloc((size_t)128 * KPAD2 * 2);
    int*   deg    = (int*)alloc((size_t)T_ * N_ * 4);
    int*   offs   = (int*)alloc((size_t)T_ * (N_ + 1) * 4);
    int*   cursor = (int*)alloc((size_t)T_ * N_ * 4);
    int*   srcs   = (int*)alloc((size_t)T_ * E_ * 4);
    float* pooled = (float*)alloc((size_t)T_ * H_ * 4);
    float* seq    = (float*)alloc((size_t)T_ * 136 * 4);
    float* Gx     = (float*)alloc((size_t)T_ * 512 * 4);

    hipMemsetAsync(deg, 0, (size_t)T_ * N_ * 4, stream);
    hipMemsetAsync(pooled, 0, (size_t)T_ * H_ * 4, stream);

    prep_w<<<(128 * KPAD1 + 255) / 256, 256, 0, stream>>>(w1, b1hi, b1lo, F_, KPAD1, 128);
    prep_w<<<(128 * KPAD2 + 255) / 256, 256, 0, stream>>>(w2, b2hi, b2lo, H_, KPAD2, 128);
    count_kernel<<<dim3(63, T_), 256, 0, stream>>>(ei, deg);
    scan_kernel<<<T_, 256, 0, stream>>>(deg, offs, cursor);
    fill_kernel<<<dim3(63, T_), 256, 0, stream>>>(ei, cursor, srcs);

    gemm_kernel<F_, KPAD1, NCH1, true><<<1000, 256, 0, stream>>>(x, b1hi, b1lo, Y);
    agg_kernel<false><<<dim3(T_, 16), 256, 0, stream>>>(Y, offs, srcs, b1, h1, nullptr);
    gemm_kernel<H_, KPAD2, NCH2, false><<<1000, 256, 0, stream>>>(h1, b2hi, b2lo, Y);
    agg_kernel<true><<<dim3(T_, 16), 256, 0, stream>>>(Y, offs, srcs, b2, nullptr, pooled);

    seq_kernel<<<(T_ * 136 + 255) / 256, 256, 0, stream>>>(pooled, emb, dok, seq);
    gx_kernel<<<256, 256, 0, stream>>>(seq, w_ih, b_ih, b_hh, Gx);
    lstm_kernel<<<1, 512, 0, stream>>>(Gx, w_hh, w_fc, b_fc, out);
}

// Round 5
// 716.462 us; speedup vs baseline: 1.7013x; 1.0932x over previous
//
#include <hip/hip_runtime.h>

#define T_ 128
#define N_ 1000
#define E_ 16000
#define F_ 397
#define H_ 128
#define KPAD1 416
#define NCH1 13
#define KPAD2 128
#define NCH2 4

typedef _Float16 f16;
typedef __attribute__((ext_vector_type(2))) _Float16 f16x2;
typedef __attribute__((ext_vector_type(4))) _Float16 f16x4;
typedef __attribute__((ext_vector_type(8))) _Float16 f16x8;
typedef __attribute__((ext_vector_type(4))) float f32x4;

// ---------------- W prep: split f32 -> f16 hi/lo, zero-pad K ----------------
__global__ void prep_w(const float* __restrict__ w, f16* __restrict__ hi,
                       f16* __restrict__ lo, int K, int KP, int rows) {
    int idx = blockIdx.x * 256 + threadIdx.x;
    if (idx >= rows * KP) return;
    int r = idx / KP, k = idx % KP;
    float v = (k < K) ? w[r * K + k] : 0.f;
    f16 h = (f16)v;
    hi[idx] = h;
    lo[idx] = (f16)(v - (float)h);
}

// ---------------- GEMM: C[M,128] = A[M,K] @ (Bhi+Blo)[128,K]^T (fp16 MFMA) --
// Reg-staged double-buffered LDS: chunk ch+1's global loads issue at the top of
// iteration ch (latency hides under ds_read+MFMA); regs->LDS[alt] after MFMA;
// ONE barrier per chunk. LDS = 2 x 30KB.
template<int K, int KP, int NCH, bool A_F32>
__global__ __launch_bounds__(256)
void gemm_kernel(const void* __restrict__ Aptr, const f16* __restrict__ Bhi,
                 const f16* __restrict__ Blo, f16* __restrict__ C) {
    __shared__ f16 lds[2 * 3 * 5120];   // [buf][A|Bh|Bl][128*40]
    int tid = threadIdx.x;
    int lane = tid & 63, wave = tid >> 6;
    int rowOff = (wave & 1) * 64, colOff = (wave >> 1) * 64;
    long blockRow = (long)blockIdx.x * 128;

    // staging registers
    float af[16];                // f32 A path: 8 rows x 2 consecutive floats
    f16x8 ah[2];                 // f16 A path: 2 rows x 8
    f16x8 bhreg[2], blreg[2];

    const int kp   = (tid & 15) * 2;   // f32 A: k-pair within chunk
    const int rA   = tid >> 4;         // f32 A: base row (0..15), rows rA+16i
    const int slot = tid & 3;          // x4 loads: 16B slot within 32-elem chunk
    const int r4   = tid >> 2;         // x4 loads: base row (0..63), rows r4+64i

#define A_LOADS(ch) do {                                                        \
    if constexpr (A_F32) {                                                      \
        const float* A = (const float*)Aptr;                                    \
        int kg = (ch) * 32 + kp;                                                \
        _Pragma("unroll")                                                       \
        for (int i = 0; i < 8; ++i) {                                           \
            const float* s = A + (blockRow + rA + i * 16) * (long)K + kg;       \
            af[2 * i]     = (kg < K)     ? s[0] : 0.f;                          \
            af[2 * i + 1] = (kg + 1 < K) ? s[1] : 0.f;                          \
        }                                                                       \
    } else {                                                                    \
        const f16* A = (const f16*)Aptr;                                        \
        _Pragma("unroll")                                                       \
        for (int i = 0; i < 2; ++i)                                             \
            ah[i] = *(const f16x8*)(A + (blockRow + r4 + i * 64) * (long)K +    \
                                    (ch) * 32 + slot * 8);                      \
    }                                                                           \
    _Pragma("unroll")                                                           \
    for (int i = 0; i < 2; ++i) {                                               \
        bhreg[i] = *(const f16x8*)(Bhi + (r4 + i * 64) * KP + (ch) * 32 + slot * 8); \
        blreg[i] = *(const f16x8*)(Blo + (r4 + i * 64) * KP + (ch) * 32 + slot * 8); \
    }                                                                           \
} while (0)

#define LDS_WRITE(buf) do {                                                     \
    f16* Al = lds + (buf) * 15360;                                              \
    f16* Bh = Al + 5120;                                                        \
    f16* Bl = Al + 10240;                                                       \
    if constexpr (A_F32) {                                                      \
        _Pragma("unroll")                                                       \
        for (int i = 0; i < 8; ++i) {                                           \
            f16x2 p; p[0] = (f16)af[2 * i]; p[1] = (f16)af[2 * i + 1];          \
            *(f16x2*)&Al[(rA + i * 16) * 40 + kp] = p;                          \
        }                                                                       \
    } else {                                                                    \
        _Pragma("unroll")                                                       \
        for (int i = 0; i < 2; ++i)                                             \
            *(f16x8*)&Al[(r4 + i * 64) * 40 + slot * 8] = ah[i];                \
    }                                                                           \
    _Pragma("unroll")                                                           \
    for (int i = 0; i < 2; ++i) {                                               \
        *(f16x8*)&Bh[(r4 + i * 64) * 40 + slot * 8] = bhreg[i];                 \
        *(f16x8*)&Bl[(r4 + i * 64) * 40 + slot * 8] = blreg[i];                 \
    }                                                                           \
} while (0)

    f32x4 acc[4][4] = {};
    A_LOADS(0);
    LDS_WRITE(0);
    __syncthreads();
    int cur = 0;
    int lrow = lane & 15, koff = (lane >> 4) * 8;
    for (int ch = 0; ch < NCH; ++ch) {
        if (ch + 1 < NCH) A_LOADS(ch + 1);   // in flight during ds_read+MFMA
        const f16* Al = lds + cur * 15360;
        const f16* Bh = Al + 5120;
        const f16* Bl = Al + 10240;
        f16x8 a[4], bh[4], bl[4];
        #pragma unroll
        for (int i = 0; i < 4; ++i) {
            a[i]  = *(const f16x8*)&Al[(rowOff + i * 16 + lrow) * 40 + koff];
            bh[i] = *(const f16x8*)&Bh[(colOff + i * 16 + lrow) * 40 + koff];
            bl[i] = *(const f16x8*)&Bl[(colOff + i * 16 + lrow) * 40 + koff];
        }
        #pragma unroll
        for (int i = 0; i < 4; ++i)
            #pragma unroll
            for (int j = 0; j < 4; ++j) {
                acc[i][j] = __builtin_amdgcn_mfma_f32_16x16x32_f16(a[i], bh[j], acc[i][j], 0, 0, 0);
                acc[i][j] = __builtin_amdgcn_mfma_f32_16x16x32_f16(a[i], bl[j], acc[i][j], 0, 0, 0);
            }
        if (ch + 1 < NCH) {
            LDS_WRITE(cur ^ 1);              // auto vmcnt-wait on staging regs
            __syncthreads();                 // single barrier per chunk
            cur ^= 1;
        }
    }
#undef A_LOADS
#undef LDS_WRITE
    int lcol = lane & 15, rbase = (lane >> 4) * 4;
    #pragma unroll
    for (int i = 0; i < 4; ++i)
        #pragma unroll
        for (int j = 0; j < 4; ++j)
            #pragma unroll
            for (int r = 0; r < 4; ++r) {
                long row = blockRow + rowOff + i * 16 + rbase + r;
                C[row * 128 + colOff + j * 16 + lcol] = (f16)acc[i][j][r];
            }
}

// ---------------- CSR build ----------------
__global__ void count_kernel(const int* __restrict__ ei, int* __restrict__ deg) {
    int t = blockIdx.y;
    int e = blockIdx.x * 256 + threadIdx.x;
    if (e < E_) {
        int dst = ei[(t * 2 + 1) * E_ + e];
        atomicAdd(&deg[t * N_ + dst], 1);
    }
}

__global__ void scan_kernel(const int* __restrict__ deg, int* __restrict__ offs,
                            int* __restrict__ cursor) {
    int t = blockIdx.x, tid = threadIdx.x;
    __shared__ int s[256];
    int d[4], sum = 0;
    #pragma unroll
    for (int q = 0; q < 4; ++q) {
        int idx = tid * 4 + q;
        d[q] = (idx < N_) ? deg[t * N_ + idx] : 0;
        sum += d[q];
    }
    s[tid] = sum;
    __syncthreads();
    for (int off = 1; off < 256; off <<= 1) {
        int v = (tid >= off) ? s[tid - off] : 0;
        __syncthreads();
        s[tid] += v;
        __syncthreads();
    }
    int excl = s[tid] - sum;
    #pragma unroll
    for (int q = 0; q < 4; ++q) {
        int idx = tid * 4 + q;
        if (idx < N_) { offs[t * (N_ + 1) + idx] = excl; cursor[t * N_ + idx] = excl; }
        excl += d[q];
    }
    if (tid == 255) offs[t * (N_ + 1) + N_] = excl;
}

__global__ void fill_kernel(const int* __restrict__ ei, int* __restrict__ cursor,
                            int* __restrict__ srcs) {
    int t = blockIdx.y;
    int e = blockIdx.x * 256 + threadIdx.x;
    if (e < E_) {
        int src = ei[t * 2 * E_ + e];
        int dst = ei[(t * 2 + 1) * E_ + e];
        int pos = atomicAdd(&cursor[t * N_ + dst], 1);
        srcs[t * E_ + pos] = src;
    }
}

// ------- agg: h = relu(Y[n] + sum_{src->n} Y[src] + b); optional mean-pool ----
__device__ __forceinline__ f32x4 cvt4(f16x4 v) {
    f32x4 r;
    r[0] = (float)v[0]; r[1] = (float)v[1]; r[2] = (float)v[2]; r[3] = (float)v[3];
    return r;
}

template<bool POOL>
__global__ __launch_bounds__(256)
void agg_kernel(const f16* __restrict__ Yin, const int* __restrict__ offs,
                const int* __restrict__ srcs, const float* __restrict__ bias,
                f16* __restrict__ hout, float* __restrict__ pooled) {
    __shared__ f32x4 pl[8][32];
    int t = blockIdx.x, nb = blockIdx.y;
    int tid = threadIdx.x;
    int g = tid >> 5, l = tid & 31;           // group, lane-in-group
    const f16* __restrict__ Yt = Yin + (size_t)t * N_ * H_ + l * 4;
    const int* __restrict__ offt = offs + t * (N_ + 1);
    const int* __restrict__ srct = srcs + t * E_;
    f32x4 bv = *(const f32x4*)&bias[l * 4];
    f32x4 pacc = {0.f, 0.f, 0.f, 0.f};

    #pragma unroll
    for (int i = 0; i < 8; ++i) {
        int n = nb * 64 + g * 8 + i;
        if (n < N_) {
            int rs = offt[n], re = offt[n + 1];
            f32x4 acc  = cvt4(*(const f16x4*)&Yt[(size_t)n * H_]);  // self
            f32x4 acc2 = {0.f, 0.f, 0.f, 0.f};
            int e = rs;
            for (; e + 3 < re; e += 4) {
                int s0 = srct[e], s1 = srct[e + 1], s2 = srct[e + 2], s3 = srct[e + 3];
                f16x4 y0 = *(const f16x4*)&Yt[(size_t)s0 * H_];
                f16x4 y1 = *(const f16x4*)&Yt[(size_t)s1 * H_];
                f16x4 y2 = *(const f16x4*)&Yt[(size_t)s2 * H_];
                f16x4 y3 = *(const f16x4*)&Yt[(size_t)s3 * H_];
                acc  += cvt4(y0) + cvt4(y1);
                acc2 += cvt4(y2) + cvt4(y3);
            }
            for (; e < re; ++e)
                acc2 += cvt4(*(const f16x4*)&Yt[(size_t)srct[e] * H_]);
            f32x4 r = acc + acc2 + bv;
            r[0] = fmaxf(r[0], 0.f); r[1] = fmaxf(r[1], 0.f);
            r[2] = fmaxf(r[2], 0.f); r[3] = fmaxf(r[3], 0.f);
            if (POOL) {
                pacc += r;
            } else {
                f16x4 hv;
                hv[0] = (f16)r[0]; hv[1] = (f16)r[1]; hv[2] = (f16)r[2]; hv[3] = (f16)r[3];
                *(f16x4*)&hout[((size_t)t * N_ + n) * H_ + l * 4] = hv;
            }
        }
    }
    if (POOL) {
        pl[g][l] = pacc;
        __syncthreads();
        if (tid < 128) {
            const float* plf = (const float*)pl;
            float s = 0.f;
            #pragma unroll
            for (int gg = 0; gg < 8; ++gg) s += plf[gg * 128 + tid];
            atomicAdd(&pooled[t * H_ + tid], s);
        }
    }
}

// ---------------- LSTM front-end ----------------
__global__ void seq_kernel(const float* __restrict__ pooled, const float* __restrict__ emb,
                           const int* __restrict__ dok, float* __restrict__ seq) {
    int idx = blockIdx.x * 256 + threadIdx.x;
    if (idx >= T_ * 136) return;
    int t = idx / 136, dd = idx % 136;
    seq[idx] = (dd < 128) ? pooled[t * H_ + dd] * (1.0f / N_)
                          : emb[dok[t] * 8 + (dd - 128)];
}

__global__ __launch_bounds__(256)
void gx_kernel(const float* __restrict__ seq, const float* __restrict__ w_ih,
               const float* __restrict__ b_ih, const float* __restrict__ b_hh,
               float* __restrict__ Gx) {
    __shared__ float x[136];
    int t = blockIdx.x >> 1;
    int j = (blockIdx.x & 1) * 256 + threadIdx.x;
    if (threadIdx.x < 136) x[threadIdx.x] = seq[t * 136 + threadIdx.x];
    __syncthreads();
    const float* w = w_ih + (size_t)j * 136;
    float acc = b_ih[j] + b_hh[j];
    #pragma unroll 8
    for (int k = 0; k < 136; ++k) acc += w[k] * x[k];
    Gx[t * 512 + j] = acc;
}

// ---------------- LSTM recurrence: 512 threads = 4 k-slices x 128 channels ---
__device__ __forceinline__ float sigm_f(float x) {
    return __builtin_amdgcn_rcpf(1.f + __expf(-x));
}
__device__ __forceinline__ float tanh_f(float x) {
    float xx = fminf(fmaxf(x, -15.f), 15.f);
    float t = __expf(2.f * xx);
    return 1.f - 2.f * __builtin_amdgcn_rcpf(t + 1.f);
}

__global__ __launch_bounds__(512, 2)
void lstm_kernel(const float* __restrict__ Gx, const float* __restrict__ w_hh,
                 const float* __restrict__ w_fc, const float* __restrict__ b_fc,
                 float* __restrict__ out) {
    __shared__ __align__(16) float h_lds[128];
    __shared__ __align__(16) f32x4 pl[4][128];
    int tid = threadIdx.x;
    int s = tid >> 7, k = tid & 127;   // k-slice, channel
    f32x4 whh[4][8];
    #pragma unroll
    for (int g = 0; g < 4; ++g)
        #pragma unroll
        for (int q = 0; q < 8; ++q)
            whh[g][q] = *(const f32x4*)&w_hh[(g * 128 + k) * 128 + s * 32 + q * 4];
    float c = 0.f;
    float wfc0 = 0.f, wfc1 = 0.f;
    if (tid < 64) { wfc0 = w_fc[tid]; wfc1 = w_fc[64 + tid]; }
    float bfc = b_fc[0];
    float gx0 = 0.f, gx1 = 0.f, gx2 = 0.f, gx3 = 0.f;
    if (tid < 128) {
        gx0 = Gx[k]; gx1 = Gx[128 + k]; gx2 = Gx[256 + k]; gx3 = Gx[384 + k];
        h_lds[k] = 0.f;
    }
    __syncthreads();
    for (int t = 0; t < T_; ++t) {
        const f32x4* h4 = (const f32x4*)h_lds + s * 8;
        f32x4 p0 = {0,0,0,0}, p1 = {0,0,0,0}, p2 = {0,0,0,0}, p3 = {0,0,0,0};
        #pragma unroll
        for (int q = 0; q < 8; ++q) {
            f32x4 v = h4[q];
            p0 += v * whh[0][q];
            p1 += v * whh[1][q];
            p2 += v * whh[2][q];
            p3 += v * whh[3][q];
        }
        f32x4 part;
        part[0] = (p0[0] + p0[1]) + (p0[2] + p0[3]);
        part[1] = (p1[0] + p1[1]) + (p1[2] + p1[3]);
        part[2] = (p2[0] + p2[1]) + (p2[2] + p2[3]);
        part[3] = (p3[0] + p3[1]) + (p3[2] + p3[3]);
        pl[s][k] = part;
        __syncthreads();
        if (tid < 128) {
            f32x4 gsum = pl[0][k] + pl[1][k] + pl[2][k] + pl[3][k];
            float gi = gsum[0] + gx0, gf = gsum[1] + gx1;
            float gg = gsum[2] + gx2, go = gsum[3] + gx3;
            int tn = (t + 1 < T_) ? t + 1 : t;
            const float* gp = Gx + tn * 512;
            gx0 = gp[k]; gx1 = gp[128 + k]; gx2 = gp[256 + k]; gx3 = gp[384 + k];
            float fi = sigm_f(gi), ff = sigm_f(gf), fo = sigm_f(go);
            c = ff * c + fi * tanh_f(gg);
            h_lds[k] = fo * tanh_f(c);
        }
        __syncthreads();
        if (tid < 64) {
            float v = h_lds[tid] * wfc0 + h_lds[64 + tid] * wfc1;
            #pragma unroll
            for (int off = 32; off; off >>= 1) v += __shfl_down(v, off);
            if (tid == 0) out[t] = v + bfc;
        }
    }
}

// ---------------- launch ----------------
extern "C" void kernel_launch(void* const* d_in, const int* in_sizes, int n_in,
                              void* d_out, int out_size, void* d_ws, size_t ws_size,
                              hipStream_t stream) {
    const float* x    = (const float*)d_in[0];
    const int*   ei   = (const int*)d_in[1];
    const int*   dok  = (const int*)d_in[2];
    const float* w1   = (const float*)d_in[3];
    const float* b1   = (const float*)d_in[4];
    const float* w2   = (const float*)d_in[5];
    const float* b2   = (const float*)d_in[6];
    const float* emb  = (const float*)d_in[7];
    const float* w_ih = (const float*)d_in[8];
    const float* w_hh = (const float*)d_in[9];
    const float* b_ih = (const float*)d_in[10];
    const float* b_hh = (const float*)d_in[11];
    const float* w_fc = (const float*)d_in[12];
    const float* b_fc = (const float*)d_in[13];
    float* out = (float*)d_out;

    char* ws = (char*)d_ws;
    size_t off = 0;
    auto alloc = [&](size_t bytes) {
        void* p = ws + off;
        off = (off + bytes + 255) & ~(size_t)255;
        return p;
    };
    f16*   Y      = (f16*)alloc((size_t)128000 * 128 * 2);  // Y, reused as Z
    f16*   h1     = (f16*)alloc((size_t)128000 * 128 * 2);
    f16*   b1hi   = (f16*)alloc((size_t)128 * KPAD1 * 2);
    f16*   b1lo   = (f16*)alloc((size_t)128 * KPAD1 * 2);
    f16*   b2hi   = (f16*)alloc((size_t)128 * KPAD2 * 2);
    f16*   b2lo   = (f16*)alloc((size_t)128 * KPAD2 * 2);
    int*   deg    = (int*)alloc((size_t)T_ * N_ * 4);
    int*   offs   = (int*)alloc((size_t)T_ * (N_ + 1) * 4);
    int*   cursor = (int*)alloc((size_t)T_ * N_ * 4);
    int*   srcs   = (int*)alloc((size_t)T_ * E_ * 4);
    float* pooled = (float*)alloc((size_t)T_ * H_ * 4);
    float* seq    = (float*)alloc((size_t)T_ * 136 * 4);
    float* Gx     = (float*)alloc((size_t)T_ * 512 * 4);

    hipMemsetAsync(deg, 0, (size_t)T_ * N_ * 4, stream);
    hipMemsetAsync(pooled, 0, (size_t)T_ * H_ * 4, stream);

    prep_w<<<(128 * KPAD1 + 255) / 256, 256, 0, stream>>>(w1, b1hi, b1lo, F_, KPAD1, 128);
    prep_w<<<(128 * KPAD2 + 255) / 256, 256, 0, stream>>>(w2, b2hi, b2lo, H_, KPAD2, 128);
    count_kernel<<<dim3(63, T_), 256, 0, stream>>>(ei, deg);
    scan_kernel<<<T_, 256, 0, stream>>>(deg, offs, cursor);
    fill_kernel<<<dim3(63, T_), 256, 0, stream>>>(ei, cursor, srcs);

    gemm_kernel<F_, KPAD1, NCH1, true><<<1000, 256, 0, stream>>>(x, b1hi, b1lo, Y);
    agg_kernel<false><<<dim3(T_, 16), 256, 0, stream>>>(Y, offs, srcs, b1, h1, nullptr);
    gemm_kernel<H_, KPAD2, NCH2, false><<<1000, 256, 0, stream>>>(h1, b2hi, b2lo, Y);
    agg_kernel<true><<<dim3(T_, 16), 256, 0, stream>>>(Y, offs, srcs, b2, nullptr, pooled);

    seq_kernel<<<(T_ * 136 + 255) / 256, 256, 0, stream>>>(pooled, emb, dok, seq);
    gx_kernel<<<256, 256, 0, stream>>>(seq, w_ih, b_ih, b_hh, Gx);
    lstm_kernel<<<1, 512, 0, stream>>>(Gx, w_hh, w_fc, b_fc, out);
}

// Round 10
// 689.172 us; speedup vs baseline: 1.7687x; 1.0396x over previous
//
#include <hip/hip_runtime.h>

#define T_ 128
#define N_ 1000
#define E_ 16000
#define F_ 397
#define H_ 128
#define NCH1 13
#define NCH2 4

typedef _Float16 f16;
typedef __attribute__((ext_vector_type(2))) _Float16 f16x2;
typedef __attribute__((ext_vector_type(4))) _Float16 f16x4;
typedef __attribute__((ext_vector_type(8))) _Float16 f16x8;
typedef __attribute__((ext_vector_type(4))) float f32x4;

// ---- W prep: split f32 -> f16 hi/lo, packed in MFMA B-fragment order -------
// Layout: frag (ch, jg, lane) at [((ch*8+jg)*64+lane)*8], holding
// W[jg*16+(lane&15)][ch*32+(lane>>4)*8 + q], q=0..7 (zero-padded past K).
template<int K, int NCH>
__global__ void prep_w_pack(const float* __restrict__ w, f16* __restrict__ hi,
                            f16* __restrict__ lo) {
    int idx = blockIdx.x * 256 + threadIdx.x;
    if (idx >= NCH * 8 * 64) return;
    int l = idx & 63, jg = (idx >> 6) & 7, ch = idx >> 9;
    int c = jg * 16 + (l & 15);
    int kb = ch * 32 + (l >> 4) * 8;
    f16x8 hv, lv;
    #pragma unroll
    for (int q = 0; q < 8; ++q) {
        int k = kb + q;
        float v = (k < K) ? w[c * K + k] : 0.f;
        f16 h = (f16)v;
        hv[q] = h;
        lv[q] = (f16)(v - (float)h);
    }
    *(f16x8*)&hi[(size_t)idx * 8] = hv;
    *(f16x8*)&lo[(size_t)idx * 8] = lv;
}

// ---- GEMM: C[M,128] = A[M,K] @ (Whi+Wlo)[128,K]^T (fp16 MFMA) --------------
// A: reg-staged double-buffered LDS (20 KB), prefetch distance 1.
// B: direct from L2 in fragment order (issued before A-prefetch so the MFMA's
//    vmcnt wait for B does not drain the in-flight A loads).
template<int K, int NCH, bool A_F32>
__global__ __launch_bounds__(256, 3)
void gemm_kernel(const void* __restrict__ Aptr, const f16* __restrict__ Bhp,
                 const f16* __restrict__ Blp, f16* __restrict__ C) {
    __shared__ f16 lds[2 * 128 * 40];   // A only, dbuf, 32k+8pad per row
    int tid = threadIdx.x;
    int lane = tid & 63, wave = tid >> 6;
    int rowOff = (wave & 1) * 64, colOff = (wave >> 1) * 64;
    long blockRow = (long)blockIdx.x * 128;

    float af[16];                // f32 A staging: 8 rows x 2 floats
    f16x8 ah[2];                 // f16 A staging: 2 rows x 8

    const int kp   = (tid & 15) * 2;   // f32 A: k-pair within chunk
    const int rA   = tid >> 4;         // f32 A: base row, rows rA+16i
    const int slot = tid & 3;          // f16 A: 16B slot within 32-elem chunk
    const int r4   = tid >> 2;         // f16 A: base row, rows r4+64i

#define A_LOADS(ch) do {                                                        \
    if constexpr (A_F32) {                                                      \
        const float* A = (const float*)Aptr;                                    \
        int kg = (ch) * 32 + kp;                                                \
        _Pragma("unroll")                                                       \
        for (int i = 0; i < 8; ++i) {                                           \
            const float* s = A + (blockRow + rA + i * 16) * (long)K + kg;       \
            af[2 * i]     = (kg < K)     ? s[0] : 0.f;                          \
            af[2 * i + 1] = (kg + 1 < K) ? s[1] : 0.f;                          \
        }                                                                       \
    } else {                                                                    \
        const f16* A = (const f16*)Aptr;                                        \
        _Pragma("unroll")                                                       \
        for (int i = 0; i < 2; ++i)                                             \
            ah[i] = *(const f16x8*)(A + (blockRow + r4 + i * 64) * (long)K +    \
                                    (ch) * 32 + slot * 8);                      \
    }                                                                           \
} while (0)

#define LDS_WRITE(buf) do {                                                     \
    f16* Al = lds + (buf) * 5120;                                               \
    if constexpr (A_F32) {                                                      \
        _Pragma("unroll")                                                       \
        for (int i = 0; i < 8; ++i) {                                           \
            f16x2 p; p[0] = (f16)af[2 * i]; p[1] = (f16)af[2 * i + 1];          \
            *(f16x2*)&Al[(rA + i * 16) * 40 + kp] = p;                          \
        }                                                                       \
    } else {                                                                    \
        _Pragma("unroll")                                                       \
        for (int i = 0; i < 2; ++i)                                             \
            *(f16x8*)&Al[(r4 + i * 64) * 40 + slot * 8] = ah[i];                \
    }                                                                           \
} while (0)

    f32x4 acc[4][4] = {};
    A_LOADS(0);
    LDS_WRITE(0);
    __syncthreads();
    int cur = 0;
    int lrow = lane & 15, koff = (lane >> 4) * 8;
    const int jg0 = colOff >> 4;
    for (int ch = 0; ch < NCH; ++ch) {
        // B frags for THIS chunk: 8 coalesced 16B loads from L2 (issued first)
        const f16* bh_base = Bhp + (((size_t)ch * 8 + jg0) * 64 + lane) * 8;
        const f16* bl_base = Blp + (((size_t)ch * 8 + jg0) * 64 + lane) * 8;
        f16x8 bh[4], bl[4];
        #pragma unroll
        for (int j = 0; j < 4; ++j) {
            bh[j] = *(const f16x8*)(bh_base + j * 512);
            bl[j] = *(const f16x8*)(bl_base + j * 512);
        }
        // prefetch A for next chunk (stays in flight through MFMA)
        if (ch + 1 < NCH) A_LOADS(ch + 1);
        const f16* Al = lds + cur * 5120;
        f16x8 a[4];
        #pragma unroll
        for (int i = 0; i < 4; ++i)
            a[i] = *(const f16x8*)&Al[(rowOff + i * 16 + lrow) * 40 + koff];
        #pragma unroll
        for (int i = 0; i < 4; ++i)
            #pragma unroll
            for (int j = 0; j < 4; ++j) {
                acc[i][j] = __builtin_amdgcn_mfma_f32_16x16x32_f16(a[i], bh[j], acc[i][j], 0, 0, 0);
                acc[i][j] = __builtin_amdgcn_mfma_f32_16x16x32_f16(a[i], bl[j], acc[i][j], 0, 0, 0);
            }
        if (ch + 1 < NCH) {
            LDS_WRITE(cur ^ 1);
            __syncthreads();
            cur ^= 1;
        }
    }
#undef A_LOADS
#undef LDS_WRITE
    int lcol = lane & 15, rbase = (lane >> 4) * 4;
    #pragma unroll
    for (int i = 0; i < 4; ++i)
        #pragma unroll
        for (int j = 0; j < 4; ++j)
            #pragma unroll
            for (int r = 0; r < 4; ++r) {
                long row = blockRow + rowOff + i * 16 + rbase + r;
                C[row * 128 + colOff + j * 16 + lcol] = (f16)acc[i][j][r];
            }
}

// ---- CSR build, fused: per-t LDS histogram -> LDS scan -> LDS-cursor fill --
__global__ __launch_bounds__(256)
void csr_kernel(const int* __restrict__ ei, int* __restrict__ offs,
                int* __restrict__ srcs) {
    __shared__ int hist[N_];
    __shared__ int s[256];
    int t = blockIdx.x, tid = threadIdx.x;
    for (int i = tid; i < N_; i += 256) hist[i] = 0;
    __syncthreads();
    const int* __restrict__ dstp = ei + (t * 2 + 1) * E_;
    const int* __restrict__ srcp = ei + t * 2 * E_;
    for (int e = tid; e < E_; e += 256) atomicAdd(&hist[dstp[e]], 1);
    __syncthreads();
    int d[4], sum = 0;
    #pragma unroll
    for (int q = 0; q < 4; ++q) {
        int idx = tid * 4 + q;
        d[q] = (idx < N_) ? hist[idx] : 0;
        sum += d[q];
    }
    s[tid] = sum;
    __syncthreads();
    for (int off = 1; off < 256; off <<= 1) {
        int v = (tid >= off) ? s[tid - off] : 0;
        __syncthreads();
        s[tid] += v;
        __syncthreads();
    }
    int excl = s[tid] - sum;
    #pragma unroll
    for (int q = 0; q < 4; ++q) {
        int idx = tid * 4 + q;
        if (idx < N_) {
            offs[t * (N_ + 1) + idx] = excl;
            hist[idx] = excl;          // reuse as cursor
        }
        excl += d[q];
    }
    if (tid == 255) offs[t * (N_ + 1) + N_] = excl;
    __syncthreads();
    for (int e = tid; e < E_; e += 256) {
        int pos = atomicAdd(&hist[dstp[e]], 1);
        srcs[t * E_ + pos] = srcp[e];
    }
}

// ------- agg: h = relu(Y[n] + sum_{src->n} Y[src] + b); optional mean-pool ----
__device__ __forceinline__ f32x4 cvt4(f16x4 v) {
    f32x4 r;
    r[0] = (float)v[0]; r[1] = (float)v[1]; r[2] = (float)v[2]; r[3] = (float)v[3];
    return r;
}

template<bool POOL>
__global__ __launch_bounds__(256)
void agg_kernel(const f16* __restrict__ Yin, const int* __restrict__ offs,
                const int* __restrict__ srcs, const float* __restrict__ bias,
                f16* __restrict__ hout, float* __restrict__ pooled) {
    __shared__ f32x4 pl[8][32];
    int t = blockIdx.x, nb = blockIdx.y;
    int tid = threadIdx.x;
    int g = tid >> 5, l = tid & 31;           // group, lane-in-group
    const f16* __restrict__ Yt = Yin + (size_t)t * N_ * H_ + l * 4;
    const int* __restrict__ offt = offs + t * (N_ + 1);
    const int* __restrict__ srct = srcs + t * E_;
    f32x4 bv = *(const f32x4*)&bias[l * 4];
    f32x4 pacc = {0.f, 0.f, 0.f, 0.f};

    #pragma unroll
    for (int i = 0; i < 8; ++i) {
        int n = nb * 64 + g * 8 + i;
        if (n < N_) {
            int rs = offt[n], re = offt[n + 1];
            f32x4 acc  = cvt4(*(const f16x4*)&Yt[(size_t)n * H_]);  // self
            f32x4 acc2 = {0.f, 0.f, 0.f, 0.f};
            int e = rs;
            for (; e + 3 < re; e += 4) {
                int s0 = srct[e], s1 = srct[e + 1], s2 = srct[e + 2], s3 = srct[e + 3];
                f16x4 y0 = *(const f16x4*)&Yt[(size_t)s0 * H_];
                f16x4 y1 = *(const f16x4*)&Yt[(size_t)s1 * H_];
                f16x4 y2 = *(const f16x4*)&Yt[(size_t)s2 * H_];
                f16x4 y3 = *(const f16x4*)&Yt[(size_t)s3 * H_];
                acc  += cvt4(y0) + cvt4(y1);
                acc2 += cvt4(y2) + cvt4(y3);
            }
            for (; e < re; ++e)
                acc2 += cvt4(*(const f16x4*)&Yt[(size_t)srct[e] * H_]);
            f32x4 r = acc + acc2 + bv;
            r[0] = fmaxf(r[0], 0.f); r[1] = fmaxf(r[1], 0.f);
            r[2] = fmaxf(r[2], 0.f); r[3] = fmaxf(r[3], 0.f);
            if (POOL) {
                pacc += r;
            } else {
                f16x4 hv;
                hv[0] = (f16)r[0]; hv[1] = (f16)r[1]; hv[2] = (f16)r[2]; hv[3] = (f16)r[3];
                *(f16x4*)&hout[((size_t)t * N_ + n) * H_ + l * 4] = hv;
            }
        }
    }
    if (POOL) {
        pl[g][l] = pacc;
        __syncthreads();
        if (tid < 128) {
            const float* plf = (const float*)pl;
            float s = 0.f;
            #pragma unroll
            for (int gg = 0; gg < 8; ++gg) s += plf[gg * 128 + tid];
            atomicAdd(&pooled[t * H_ + tid], s);
        }
    }
}

// ---------------- LSTM x-path: Gx[t] = W_ih @ seq[t] + b_ih + b_hh ----------
__global__ __launch_bounds__(256)
void gx_kernel(const float* __restrict__ pooled, const float* __restrict__ emb,
               const int* __restrict__ dok, const float* __restrict__ w_ih,
               const float* __restrict__ b_ih, const float* __restrict__ b_hh,
               float* __restrict__ Gx) {
    __shared__ float x[136];
    int t = blockIdx.x >> 1;
    int j = (blockIdx.x & 1) * 256 + threadIdx.x;
    if (threadIdx.x < 128) x[threadIdx.x] = pooled[t * H_ + threadIdx.x] * (1.0f / N_);
    else if (threadIdx.x < 136) x[threadIdx.x] = emb[dok[t] * 8 + threadIdx.x - 128];
    __syncthreads();
    const float* w = w_ih + (size_t)j * 136;
    float acc = b_ih[j] + b_hh[j];
    #pragma unroll 8
    for (int k = 0; k < 136; ++k) acc += w[k] * x[k];
    Gx[t * 512 + j] = acc;
}

// ---------------- LSTM recurrence: 512 threads = 4 k-slices x 128 channels ---
__device__ __forceinline__ float sigm_f(float x) {
    return __builtin_amdgcn_rcpf(1.f + __expf(-x));
}
__device__ __forceinline__ float tanh_f(float x) {
    float xx = fminf(fmaxf(x, -15.f), 15.f);
    float t = __expf(2.f * xx);
    return 1.f - 2.f * __builtin_amdgcn_rcpf(t + 1.f);
}

__global__ __launch_bounds__(512, 2)
void lstm_kernel(const float* __restrict__ Gx, const float* __restrict__ w_hh,
                 const float* __restrict__ w_fc, const float* __restrict__ b_fc,
                 float* __restrict__ out) {
    __shared__ __align__(16) float h_lds[128];
    __shared__ __align__(16) f32x4 pl[4][128];
    int tid = threadIdx.x;
    int s = tid >> 7, k = tid & 127;   // k-slice, channel
    f32x4 whh[4][8];
    #pragma unroll
    for (int g = 0; g < 4; ++g)
        #pragma unroll
        for (int q = 0; q < 8; ++q)
            whh[g][q] = *(const f32x4*)&w_hh[(g * 128 + k) * 128 + s * 32 + q * 4];
    float c = 0.f;
    float wfc0 = 0.f, wfc1 = 0.f;
    if (tid < 64) { wfc0 = w_fc[tid]; wfc1 = w_fc[64 + tid]; }
    float bfc = b_fc[0];
    float gx0 = 0.f, gx1 = 0.f, gx2 = 0.f, gx3 = 0.f;
    if (tid < 128) {
        gx0 = Gx[k]; gx1 = Gx[128 + k]; gx2 = Gx[256 + k]; gx3 = Gx[384 + k];
        h_lds[k] = 0.f;
    }
    __syncthreads();
    for (int t = 0; t < T_; ++t) {
        const f32x4* h4 = (const f32x4*)h_lds + s * 8;
        f32x4 p0 = {0,0,0,0}, p1 = {0,0,0,0}, p2 = {0,0,0,0}, p3 = {0,0,0,0};
        #pragma unroll
        for (int q = 0; q < 8; ++q) {
            f32x4 v = h4[q];
            p0 += v * whh[0][q];
            p1 += v * whh[1][q];
            p2 += v * whh[2][q];
            p3 += v * whh[3][q];
        }
        f32x4 part;
        part[0] = (p0[0] + p0[1]) + (p0[2] + p0[3]);
        part[1] = (p1[0] + p1[1]) + (p1[2] + p1[3]);
        part[2] = (p2[0] + p2[1]) + (p2[2] + p2[3]);
        part[3] = (p3[0] + p3[1]) + (p3[2] + p3[3]);
        pl[s][k] = part;
        __syncthreads();
        if (tid < 128) {
            f32x4 gsum = pl[0][k] + pl[1][k] + pl[2][k] + pl[3][k];
            float gi = gsum[0] + gx0, gf = gsum[1] + gx1;
            float gg = gsum[2] + gx2, go = gsum[3] + gx3;
            int tn = (t + 1 < T_) ? t + 1 : t;
            const float* gp = Gx + tn * 512;
            gx0 = gp[k]; gx1 = gp[128 + k]; gx2 = gp[256 + k]; gx3 = gp[384 + k];
            float fi = sigm_f(gi), ff = sigm_f(gf), fo = sigm_f(go);
            c = ff * c + fi * tanh_f(gg);
            h_lds[k] = fo * tanh_f(c);
        }
        __syncthreads();
        if (tid < 64) {
            float v = h_lds[tid] * wfc0 + h_lds[64 + tid] * wfc1;
            #pragma unroll
            for (int off = 32; off; off >>= 1) v += __shfl_down(v, off);
            if (tid == 0) out[t] = v + bfc;
        }
    }
}

// ---------------- launch ----------------
extern "C" void kernel_launch(void* const* d_in, const int* in_sizes, int n_in,
                              void* d_out, int out_size, void* d_ws, size_t ws_size,
                              hipStream_t stream) {
    const float* x    = (const float*)d_in[0];
    const int*   ei   = (const int*)d_in[1];
    const int*   dok  = (const int*)d_in[2];
    const float* w1   = (const float*)d_in[3];
    const float* b1   = (const float*)d_in[4];
    const float* w2   = (const float*)d_in[5];
    const float* b2   = (const float*)d_in[6];
    const float* emb  = (const float*)d_in[7];
    const float* w_ih = (const float*)d_in[8];
    const float* w_hh = (const float*)d_in[9];
    const float* b_ih = (const float*)d_in[10];
    const float* b_hh = (const float*)d_in[11];
    const float* w_fc = (const float*)d_in[12];
    const float* b_fc = (const float*)d_in[13];
    float* out = (float*)d_out;

    char* ws = (char*)d_ws;
    size_t off = 0;
    auto alloc = [&](size_t bytes) {
        void* p = ws + off;
        off = (off + bytes + 255) & ~(size_t)255;
        return p;
    };
    f16*   Y      = (f16*)alloc((size_t)128000 * 128 * 2);  // Y, reused as Z
    f16*   h1     = (f16*)alloc((size_t)128000 * 128 * 2);
    f16*   b1hi   = (f16*)alloc((size_t)NCH1 * 8 * 64 * 8 * 2);
    f16*   b1lo   = (f16*)alloc((size_t)NCH1 * 8 * 64 * 8 * 2);
    f16*   b2hi   = (f16*)alloc((size_t)NCH2 * 8 * 64 * 8 * 2);
    f16*   b2lo   = (f16*)alloc((size_t)NCH2 * 8 * 64 * 8 * 2);
    int*   offs   = (int*)alloc((size_t)T_ * (N_ + 1) * 4);
    int*   srcs   = (int*)alloc((size_t)T_ * E_ * 4);
    float* pooled = (float*)alloc((size_t)T_ * H_ * 4);
    float* Gx     = (float*)alloc((size_t)T_ * 512 * 4);

    hipMemsetAsync(pooled, 0, (size_t)T_ * H_ * 4, stream);

    prep_w_pack<F_, NCH1><<<(NCH1 * 8 * 64 + 255) / 256, 256, 0, stream>>>(w1, b1hi, b1lo);
    prep_w_pack<H_, NCH2><<<(NCH2 * 8 * 64 + 255) / 256, 256, 0, stream>>>(w2, b2hi, b2lo);
    csr_kernel<<<T_, 256, 0, stream>>>(ei, offs, srcs);

    gemm_kernel<F_, NCH1, true><<<1000, 256, 0, stream>>>(x, b1hi, b1lo, Y);
    agg_kernel<false><<<dim3(T_, 16), 256, 0, stream>>>(Y, offs, srcs, b1, h1, nullptr);
    gemm_kernel<H_, NCH2, false><<<1000, 256, 0, stream>>>(h1, b2hi, b2lo, Y);
    agg_kernel<true><<<dim3(T_, 16), 256, 0, stream>>>(Y, offs, srcs, b2, nullptr, pooled);

    gx_kernel<<<256, 256, 0, stream>>>(pooled, emb, dok, w_ih, b_ih, b_hh, Gx);
    lstm_kernel<<<1, 512, 0, stream>>>(Gx, w_hh, w_fc, b_fc, out);
}